// Round 12
// baseline (224.479 us; speedup 1.0000x reference)
//
#include <hip/hip_runtime.h>
#include <cfloat>
#include <cstdint>

// ---------------- problem constants ----------------
#define B_BATCH 32
#define D_DIM   256
#define HW      1024
#define N_POS   32768
#define K_CODES 1024
#define DECAY_F   0.99f
#define ONE_M_DECAY 0.01f
#define EPS_F   1e-5f

// ---------------- output layout (floats) ----------------
#define OUT_Q    0                         // 8388608  quantized_st (B,C,H,W)
#define OUT_LOSS 8388608                   // 1
#define OUT_PERP 8388609                   // 1
#define OUT_CB   8388610                   // 262144   new_codebook
#define OUT_NCS  8650754                   // 1024     new_cluster_size
#define OUT_EDW  8651778                   // 262144   new_ema_dw (dw scratch first)

// OUT_Q region doubles as z bf16 hi/lo scratch (exactly 33,554,432 bytes):
// ztrans writes zhi (16 MB) + zlo (16 MB); argmin_gemm + dw read them;
// tail_fused overwrites the region with the real output at the end.

// ---------------- workspace layout (bytes) ----------------
// NOTE: no memset needed -- every cell below is fully written before read:
//   counts/offsets/cursor/ncs by combine2's last block; znorm_parts by prep;
//   hist/bsum_parts by combine2 phase 1; done_ctr zeroed by prep block 0.
#define WS_COUNTS  0          // 1024*4
#define WS_CBNORM  4352       // 1024*4
#define WS_OFFS    8448       // 1024*4 (int)
#define WS_CURSOR  12544      // 1024*4 (int)
#define WS_IDX     16640      // 32768*4 (int)
#define WS_SORTED  147712     // 32768*4 (int)
#define WS_CBHI    278784     // 262144*2
#define WS_CBLO    803072     // 262144*2
#define WS_PART    1327360    // 32768*4*8 = 1048576 (u64 partial keys)
#define WS_HIST    2375936    // 128*1024*4 = 524288 (per-block histograms)
#define WS_ZPART   2900224    // 512*4 (per-block ||z||^2 partials)
#define WS_BPART   2902272    // 128*4 (per-block bsum partials)
#define WS_DONE    2902784    // 4 (combine2 ticket counter; zeroed by prep)
#define WS_NTOT    2902788    // 4 (ntot scalar)
#define WS_SCODE   3424512    // 32768*4 (int, code of each sorted slot)
#define WS_TOTAL   3555584

typedef short s16x8 __attribute__((ext_vector_type(8)));
typedef float f32x4 __attribute__((ext_vector_type(4)));
typedef unsigned long long u64;

__device__ __forceinline__ ushort f2bf_rne(float x) {
    uint u = __float_as_uint(x);
    uint r = (u + 0x7FFF + ((u >> 16) & 1)) >> 16;
    return (ushort)r;
}
__device__ __forceinline__ float bf2f(ushort h) {
    return __uint_as_float(((uint)h) << 16);
}

// async global->LDS, 16 B per lane; LDS dst = wave-uniform base + lane*16
__device__ __forceinline__ void gload16(const void* g, void* l) {
    __builtin_amdgcn_global_load_lds(
        (const __attribute__((address_space(1))) unsigned*)(uintptr_t)g,
        (__attribute__((address_space(3))) unsigned*)(uintptr_t)l, 16, 0, 0);
}

// ============================================================
// prep_ztrans (R10-passing body; znorm now a per-block plain store, and
// block 0 zeroes the combine2 ticket counter -- no hipMemsetAsync needed).
//  blocks [0,512):  z (d-major) -> zhi/zlo bf16 (position-major), 64 pos/blk
//  blocks [512,768): codebook fp32 -> bf16 hi/lo + row norms
__global__ __launch_bounds__(256) void prep_ztrans(const float* __restrict__ z,
                                                   const float* __restrict__ cb,
                                                   ushort* __restrict__ zhi,
                                                   ushort* __restrict__ zlo,
                                                   ushort* __restrict__ cbhi,
                                                   ushort* __restrict__ cblo,
                                                   float* __restrict__ cbnorm,
                                                   float* __restrict__ znorm_parts,
                                                   int* __restrict__ done_ctr) {
    __shared__ float Zs[2][32][68];   // 2 x 8704 B; rows 16B-aligned
    __shared__ float red[256];
    const int tid = threadIdx.x;

    if (blockIdx.x == 0 && tid == 0) *done_ctr = 0;   // stream-ordered before combine2

    if (blockIdx.x >= 512) {   // ---- codebook part ----
        int wave = tid >> 6;
        int lane = tid & 63;
        int k = (blockIdx.x - 512) * 4 + wave;
        float4 v = *(const float4*)&cb[(size_t)k * D_DIM + lane * 4];
        ushort4 h, l;
        h.x = f2bf_rne(v.x); l.x = f2bf_rne(v.x - bf2f(h.x));
        h.y = f2bf_rne(v.y); l.y = f2bf_rne(v.y - bf2f(h.y));
        h.z = f2bf_rne(v.z); l.z = f2bf_rne(v.z - bf2f(h.z));
        h.w = f2bf_rne(v.w); l.w = f2bf_rne(v.w - bf2f(h.w));
        *(ushort4*)&cbhi[(size_t)k * D_DIM + lane * 4] = h;
        *(ushort4*)&cblo[(size_t)k * D_DIM + lane * 4] = l;
        float s = v.x * v.x + v.y * v.y + v.z * v.z + v.w * v.w;
        #pragma unroll
        for (int off = 32; off >= 1; off >>= 1) s += __shfl_xor(s, off);
        if (lane == 0) cbnorm[k] = s;
        return;
    }

    // ---- z transpose part: 64 positions per block ----
    const int n0  = blockIdx.x * 64;
    const int b   = n0 >> 10;
    const int hw0 = n0 & 1023;
    const float* zb = z + (size_t)b * (D_DIM * HW) + hw0;

    const int zd  = tid >> 4;          // 0..15 (row within pass)
    const int zcg = tid & 15;          // float4 column group
    const int ga  = zcg ^ (((zd >> 3) & 3) << 1);          // row zd swizzle
    const int gb  = zcg ^ ((((zd + 16) >> 3) & 3) << 1);   // row zd+16 swizzle
    const int n   = tid >> 2;          // 0..63 (conversion: position)
    const int dq  = tid & 3;           // conversion: dim quarter
    const int zcol = (((n >> 2) ^ (dq << 1)) << 2) | (n & 3);
    float zsum = 0.f;

    // prologue: iter 0's tile into buffer 0
    {
        float4 va = *(const float4*)&zb[(size_t)zd * HW + zcg * 4];
        float4 vb = *(const float4*)&zb[(size_t)(zd + 16) * HW + zcg * 4];
        *(float4*)&Zs[0][zd][ga * 4] = va;
        *(float4*)&Zs[0][zd + 16][gb * 4] = vb;
    }

    for (int it = 0; it < 8; ++it) {
        const int d0 = it * 32;
        __syncthreads();
        float4 na, nb;
        if (it < 7) {
            na = *(const float4*)&zb[(size_t)(d0 + 32 + zd) * HW + zcg * 4];
            nb = *(const float4*)&zb[(size_t)(d0 + 48 + zd) * HW + zcg * 4];
        }
        {
            s16x8 hv, lv;
            #pragma unroll
            for (int j = 0; j < 8; ++j) {
                float f = Zs[it & 1][dq * 8 + j][zcol];
                zsum += f * f;
                ushort hb = f2bf_rne(f);
                ushort lb = f2bf_rne(f - bf2f(hb));
                hv[j] = (short)hb;
                lv[j] = (short)lb;
            }
            *(s16x8*)&zhi[(size_t)(n0 + n) * D_DIM + d0 + dq * 8] = hv;
            *(s16x8*)&zlo[(size_t)(n0 + n) * D_DIM + d0 + dq * 8] = lv;
        }
        if (it < 7) {
            *(float4*)&Zs[(it + 1) & 1][zd][ga * 4] = na;
            *(float4*)&Zs[(it + 1) & 1][zd + 16][gb * 4] = nb;
        }
    }
    red[tid] = zsum;
    __syncthreads();
    for (int s2 = 128; s2 >= 1; s2 >>= 1) {
        if (tid < s2) red[tid] += red[tid + s2];
        __syncthreads();
    }
    if (tid == 0) znorm_parts[blockIdx.x] = red[0];
}

// ============================================================
// argmin_gemm v5 (EXACT R4/R7/R8/R10-passing version): 256 codes x 256
// positions per block, 8 waves, each wave M8N4, 3-term bf16 MFMA, K-step 32.
// Ring-2 of 64 KB buffers = 128 KB LDS, 1 block/CU (2 waves/SIMD).
__global__ __launch_bounds__(512, 2) void argmin_gemm(const ushort* __restrict__ cbhi,
                                                      const ushort* __restrict__ cblo,
                                                      const ushort* __restrict__ zhi,
                                                      const ushort* __restrict__ zlo,
                                                      const float* __restrict__ cbnorm,
                                                      u64* __restrict__ partial) {
    // 2 x 65536 B ring (kred for the final reduction aliases buffer 0)
    __shared__ __align__(16) ushort lds[65536];   // 131072 bytes

    const int tid  = threadIdx.x;
    const int wave = tid >> 6;
    const int lane = tid & 63;
    const int col  = lane & 15;
    const int lg   = lane >> 4;
    const int wr   = wave >> 2;          // code half 0..1 (128 codes)
    const int wc   = wave & 3;           // position quarter 0..3 (64 positions)
    const int blk  = blockIdx.x;
    const int mt = (blk >> 3) & 3;                       // code tile (256 codes)
    const int pt = (blk & 7) | ((blk >> 5) << 3);        // position tile (256 pos)

    const int srow = tid >> 2;
    const int G    = tid & 3;
    const int sg   = (G ^ ((srow >> 1) & 3)) * 16;   // swizzled source byte group
    const char* pAh = (const char*)cbhi + (size_t)(mt * 256 + srow) * 512 + sg;
    const char* pAl = (const char*)cblo + (size_t)(mt * 256 + srow) * 512 + sg;
    const char* pBh = (const char*)zhi  + (size_t)(pt * 256 + srow) * 512 + sg;
    const char* pBl = (const char*)zlo  + (size_t)(pt * 256 + srow) * 512 + sg;
    char* const ldsw = (char*)lds + wave * 1024;      // wave-uniform dest base

    auto stage_q = [&](int kt, int bsel, int q) {
        char* d = ldsw + bsel * 65536;
        const int kb = kt * 64;
        if (q == 0)      { gload16(pAh + kb, d);         gload16(pAh + kb + 65536, d + 8192);  }
        else if (q == 1) { gload16(pAl + kb, d + 16384); gload16(pAl + kb + 65536, d + 24576); }
        else if (q == 2) { gload16(pBh + kb, d + 32768); gload16(pBh + kb + 65536, d + 40960); }
        else             { gload16(pBl + kb, d + 49152); gload16(pBl + kb + 65536, d + 57344); }
    };

    const char* ldsc = (const char*)lds;
    const int swz  = (lg ^ ((col >> 1) & 3)) * 16;
    const int aoff = (wr * 128 + col) * 64 + swz;    // in Ahi region (row < 256)
    const int boff = (wc * 64 + col) * 64 + swz;     // in Bhi region (row < 256)

    f32x4 acc[8][4];
    #pragma unroll
    for (int mi = 0; mi < 8; ++mi)
        #pragma unroll
        for (int ni = 0; ni < 4; ++ni) acc[mi][ni] = {0.f, 0.f, 0.f, 0.f};

    // prologue: tile 0 in flight (8 gloads)
    stage_q(0, 0, 0); stage_q(0, 0, 1); stage_q(0, 0, 2); stage_q(0, 0, 3);

#define MM3A(AH, AL, mi, ni)                                                                   \
    acc[mi][ni] = __builtin_amdgcn_mfma_f32_16x16x32_bf16(AH, bh[ni], acc[mi][ni], 0, 0, 0);   \
    acc[mi][ni] = __builtin_amdgcn_mfma_f32_16x16x32_bf16(AH, bl[ni], acc[mi][ni], 0, 0, 0);   \
    acc[mi][ni] = __builtin_amdgcn_mfma_f32_16x16x32_bf16(AL, bh[ni], acc[mi][ni], 0, 0, 0);
#define ROW3(AH, AL, mi) MM3A(AH, AL, mi, 0) MM3A(AH, AL, mi, 1) MM3A(AH, AL, mi, 2) MM3A(AH, AL, mi, 3)

    #pragma unroll
    for (int t = 0; t < 8; ++t) {
        asm volatile("s_waitcnt vmcnt(0)" ::: "memory");
        __builtin_amdgcn_s_barrier();
        __builtin_amdgcn_sched_barrier(0);

        const char* bp = ldsc + (t & 1) * 65536;
        const int nb = (t + 1) & 1;
        s16x8 bh[4], bl[4];
        s16x8 ah0, al0, ah1, al1;

        // ---- P0: all B operands + A-pair 0 (m0,m1); stage quarter 0
        bh[0] = *(const s16x8*)(bp + 32768 + boff);
        bl[0] = *(const s16x8*)(bp + 49152 + boff);
        bh[1] = *(const s16x8*)(bp + 32768 + boff + 1024);
        bl[1] = *(const s16x8*)(bp + 49152 + boff + 1024);
        bh[2] = *(const s16x8*)(bp + 32768 + boff + 2048);
        bl[2] = *(const s16x8*)(bp + 49152 + boff + 2048);
        bh[3] = *(const s16x8*)(bp + 32768 + boff + 3072);
        bl[3] = *(const s16x8*)(bp + 49152 + boff + 3072);
        ah0 = *(const s16x8*)(bp + aoff);
        al0 = *(const s16x8*)(bp + 16384 + aoff);
        ah1 = *(const s16x8*)(bp + aoff + 1024);
        al1 = *(const s16x8*)(bp + 16384 + aoff + 1024);
        if (t < 7) stage_q(t + 1, nb, 0);
        __builtin_amdgcn_s_setprio(1);
        ROW3(ah0, al0, 0) ROW3(ah1, al1, 1)
        __builtin_amdgcn_s_setprio(0);

        // ---- P1: A-pair 1 (m2,m3); stage quarter 1
        ah0 = *(const s16x8*)(bp + aoff + 2048);
        al0 = *(const s16x8*)(bp + 16384 + aoff + 2048);
        ah1 = *(const s16x8*)(bp + aoff + 3072);
        al1 = *(const s16x8*)(bp + 16384 + aoff + 3072);
        if (t < 7) stage_q(t + 1, nb, 1);
        __builtin_amdgcn_s_setprio(1);
        ROW3(ah0, al0, 2) ROW3(ah1, al1, 3)
        __builtin_amdgcn_s_setprio(0);

        // ---- P2: A-pair 2 (m4,m5); stage quarter 2
        ah0 = *(const s16x8*)(bp + aoff + 4096);
        al0 = *(const s16x8*)(bp + 16384 + aoff + 4096);
        ah1 = *(const s16x8*)(bp + aoff + 5120);
        al1 = *(const s16x8*)(bp + 16384 + aoff + 5120);
        if (t < 7) stage_q(t + 1, nb, 2);
        __builtin_amdgcn_s_setprio(1);
        ROW3(ah0, al0, 4) ROW3(ah1, al1, 5)
        __builtin_amdgcn_s_setprio(0);

        // ---- P3: A-pair 3 (m6,m7); stage quarter 3
        ah0 = *(const s16x8*)(bp + aoff + 6144);
        al0 = *(const s16x8*)(bp + 16384 + aoff + 6144);
        ah1 = *(const s16x8*)(bp + aoff + 7168);
        al1 = *(const s16x8*)(bp + 16384 + aoff + 7168);
        if (t < 7) stage_q(t + 1, nb, 3);
        __builtin_amdgcn_s_setprio(1);
        ROW3(ah0, al0, 6) ROW3(ah1, al1, 7)
        __builtin_amdgcn_s_setprio(0);
    }
#undef ROW3
#undef MM3A

    // ---- argmin epilogue (C layout: code = kbase + mi*16 + lg*4 + r,
    // pos = pt*256 + wc*64 + ni*16 + col)
    const int kbase = mt * 256 + wr * 128;
    u64 best[4] = {~0ull, ~0ull, ~0ull, ~0ull};
    #pragma unroll
    for (int mi = 0; mi < 8; ++mi) {
        float4 cn = *(const float4*)&cbnorm[kbase + mi * 16 + lg * 4];
        const float* cnp = (const float*)&cn;
        #pragma unroll
        for (int ni = 0; ni < 4; ++ni) {
            #pragma unroll
            for (int r = 0; r < 4; ++r) {
                float dist = cnp[r] - 2.f * acc[mi][ni][r];
                uint ub = __float_as_uint(dist);
                ub = ub ^ (uint)(((int)ub >> 31) | 0x80000000);
                u64 key = ((u64)ub << 32) | (uint)(kbase + mi * 16 + lg * 4 + r);
                if (key < best[ni]) best[ni] = key;
            }
        }
    }
    #pragma unroll
    for (int ni = 0; ni < 4; ++ni) {
        u64 o = __shfl_xor(best[ni], 16); if (o < best[ni]) best[ni] = o;
        o = __shfl_xor(best[ni], 32); if (o < best[ni]) best[ni] = o;
    }
    u64* kredp = (u64*)lds;
    if (lane < 16) {
        #pragma unroll
        for (int ni = 0; ni < 4; ++ni)
            kredp[(wc * 64 + ni * 16 + lane) * 2 + wr] = best[ni];
    }
    __syncthreads();
    if (tid < 256) {
        u64 a = kredp[tid * 2 + 0];
        u64 b = kredp[tid * 2 + 1]; if (b < a) a = b;
        partial[(size_t)(pt * 256 + tid) * 4 + mt] = a;
    }
}

// ============================================================
// combine2: fuses combine + small into one dispatch via the fence+ticket
// last-block pattern (no spin -> deadlock-free, dispatch-order independent).
// Phase 1 (all 128 blocks): min over 4 code-tile partials -> idx; per-block
//   LDS histogram -> hist_ws[blk]; block bsum -> bsum_parts[blk].
// Phase 2 (last block only, 256 threads): counts (4 codes/thread), ncs,
//   perplexity, ntot, loss (sums znorm_parts + bsum_parts), and the
//   offsets/cursor prefix scan (integer-identical to the old 1024-thread scan).
__global__ __launch_bounds__(256) void combine2(const u64* __restrict__ partial,
                                                int* __restrict__ idx,
                                                const float* __restrict__ ema_cs,
                                                const float* __restrict__ znorm_parts,
                                                float* __restrict__ bsum_parts,
                                                int* __restrict__ hist_ws,
                                                int* __restrict__ done_ctr,
                                                float* __restrict__ counts,
                                                float* __restrict__ out_ncs,
                                                float* __restrict__ out_perp,
                                                float* __restrict__ out_loss,
                                                float* __restrict__ ntot_ws,
                                                int* __restrict__ offsets,
                                                int* __restrict__ cursor) {
    __shared__ int hist[1024];
    __shared__ float red[256];
    __shared__ float red2[256];
    __shared__ int sc[256];
    __shared__ int ticket_s;
    const int tid = threadIdx.x;
    const int blk = blockIdx.x;

    // ---- phase 1: per-block combine ----
    for (int j = tid; j < 1024; j += 256) hist[j] = 0;
    __syncthreads();
    int n = blk * 256 + tid;
    const u64* p = partial + (size_t)n * 4;
    u64 m = p[0];
    #pragma unroll
    for (int j = 1; j < 4; ++j) { u64 v = p[j]; if (v < m) m = v; }
    int k = (int)(m & 1023u);
    idx[n] = k;
    atomicAdd(&hist[k], 1);
    uint ub = (uint)(m >> 32);
    uint u = (ub & 0x80000000u) ? (ub ^ 0x80000000u) : ~ub;
    red[tid] = __uint_as_float(u);
    __syncthreads();
    for (int s2 = 128; s2 >= 1; s2 >>= 1) {
        if (tid < s2) red[tid] += red[tid + s2];
        __syncthreads();
    }
    if (tid == 0) bsum_parts[blk] = red[0];
    for (int j = tid; j < 1024; j += 256) hist_ws[blk * 1024 + j] = hist[j];

    // ---- ticket gate ----
    __threadfence();                 // publish idx/hist/bsum before the ticket
    __syncthreads();
    if (tid == 0) ticket_s = atomicAdd(done_ctr, 1);
    __syncthreads();
    if (ticket_s != 127) return;
    __threadfence();                 // acquire side: see all blocks' stores

    // ---- phase 2: last block does small_kernel's work (256 thr, 4 codes ea) ----
    float s1 = 0.f, s2 = 0.f;
    int loc[4];
    int tot = 0;
    #pragma unroll
    for (int j = 0; j < 4; ++j) {
        int k4 = tid * 4 + j;
        int c = 0;
        for (int b2 = 0; b2 < 128; ++b2) c += hist_ws[b2 * 1024 + k4];
        counts[k4] = (float)c;
        float ncs = ema_cs[k4] * DECAY_F + ONE_M_DECAY * (float)c;
        out_ncs[k4] = ncs;
        s1 += ncs;
        float pp = (float)c / (float)N_POS;
        s2 += pp * logf(pp + 1e-10f);
        loc[j] = tot;
        tot += c;
    }
    sc[tid] = tot;
    __syncthreads();
    for (int off = 1; off < 256; off <<= 1) {
        int v = (tid >= off) ? sc[tid - off] : 0;
        __syncthreads();
        sc[tid] += v;
        __syncthreads();
    }
    int excl = sc[tid] - tot;
    #pragma unroll
    for (int j = 0; j < 4; ++j) {
        offsets[tid * 4 + j] = excl + loc[j];
        cursor[tid * 4 + j]  = excl + loc[j];
    }
    // reductions: s1 (ntot), s2 (entropy), znorm (512 parts), bsum (128 parts)
    red[tid]  = s1;
    red2[tid] = s2;
    __syncthreads();
    for (int st = 128; st >= 1; st >>= 1) {
        if (tid < st) { red[tid] += red[tid + st]; red2[tid] += red2[tid + st]; }
        __syncthreads();
    }
    float S1 = red[0], S2 = red2[0];
    __syncthreads();
    red[tid]  = znorm_parts[tid] + znorm_parts[tid + 256];
    red2[tid] = (tid < 128) ? bsum_parts[tid] : 0.f;
    __syncthreads();
    for (int st = 128; st >= 1; st >>= 1) {
        if (tid < st) { red[tid] += red[tid + st]; red2[tid] += red2[tid + st]; }
        __syncthreads();
    }
    if (tid == 0) {
        ntot_ws[0] = S1;
        out_perp[0] = expf(-S2);
        out_loss[0] = 0.25f * (red[0] + red2[0]) / 8388608.0f;
    }
}

// ============================================================
// scatter: block-aggregated bucket sort; also zeroes the dw scratch region.
__global__ __launch_bounds__(256) void scatter_kernel(const int* __restrict__ idx,
                                                      int* __restrict__ cursor,
                                                      int* __restrict__ sorted,
                                                      int* __restrict__ scode,
                                                      float* __restrict__ dw_zero) {
    __shared__ int hist[1024];
    __shared__ int base_s[1024];
    const int tid = threadIdx.x;
    // zero the dw scratch (262144 floats / 128 blocks = 8 per thread)
    {
        float4 z4 = {0.f, 0.f, 0.f, 0.f};
        size_t e = ((size_t)blockIdx.x * 256 + tid) * 8;
        *(float4*)&dw_zero[e] = z4;
        *(float4*)&dw_zero[e + 4] = z4;
    }
    for (int j = tid; j < 1024; j += 256) hist[j] = 0;
    __syncthreads();
    int n = blockIdx.x * 256 + tid;
    int k = idx[n];
    atomicAdd(&hist[k], 1);
    __syncthreads();
    for (int j = tid; j < 1024; j += 256) {
        int c = hist[j];
        if (c) base_s[j] = atomicAdd(&cursor[j], c);
        hist[j] = 0;
    }
    __syncthreads();
    int rank = atomicAdd(&hist[k], 1);
    int pos = base_s[k] + rank;
    sorted[pos] = n;
    scode[pos] = k;
}

// ============================================================
// dw_chunk v1 (R4/R8/R10-proven): uniform chunks of the SORTED array.
#define DW_CHUNK 64
__global__ __launch_bounds__(256) void dw_chunk_kernel(const ushort* __restrict__ zhi,
                                                       const ushort* __restrict__ zlo,
                                                       const int* __restrict__ sorted,
                                                       const int* __restrict__ scode,
                                                       const int* __restrict__ offsets,
                                                       const float* __restrict__ counts,
                                                       float* __restrict__ dw) {
    __shared__ int sid[DW_CHUNK];
    __shared__ int sk[DW_CHUNK];
    const int tid = threadIdx.x;
    const int p0 = blockIdx.x * DW_CHUNK;
    if (tid < DW_CHUNK) {
        sid[tid] = sorted[p0 + tid];
        sk[tid]  = scode[p0 + tid];
    }
    __syncthreads();
    float acc = 0.f;
    int runstart = 0;
    #pragma unroll 4
    for (int i = 0; i < DW_CHUNK; ++i) {
        int id = sid[i];
        float zv = bf2f(zhi[(size_t)id * D_DIM + tid]) + bf2f(zlo[(size_t)id * D_DIM + tid]);
        acc += zv;
        bool end = (i == DW_CHUNK - 1) || (sk[i + 1] != sk[i]);
        if (end) {
            int k = sk[i];
            int off = offsets[k];
            int cnt = (int)counts[k];
            if (p0 + runstart == off && p0 + i == off + cnt - 1)
                dw[(size_t)k * D_DIM + tid] = acc;
            else
                atomicAdd(&dw[(size_t)k * D_DIM + tid], acc);
            acc = 0.f;
            runstart = i + 1;
        }
    }
}

// ============================================================
// tail_fused (R4/R8/R10-proven): blocks [0,512) = fuse_lite; blocks
// [512,1536) = finalize_rows.
__global__ __launch_bounds__(256) void tail_fused(const float* __restrict__ cb,
                                                  const int* __restrict__ idx,
                                                  float* __restrict__ outq,
                                                  const float* __restrict__ ema_dw,
                                                  const float* __restrict__ out_ncs,
                                                  const float* __restrict__ ntot_ws,
                                                  float* __restrict__ out_edw,
                                                  float* __restrict__ out_cb) {
    const int tid = threadIdx.x;
    if (blockIdx.x >= 512) {      // ---- finalize part ----
        int k = blockIdx.x - 512;
        int d = tid;
        float ncs = out_ncs[k];
        float nt = ntot_ws[0];
        float csz = (ncs + EPS_F) / (nt + (float)K_CODES * EPS_F) * nt;
        size_t e = (size_t)k * D_DIM + d;
        float ed = ema_dw[e] * DECAY_F + ONE_M_DECAY * out_edw[e];
        out_edw[e] = ed;
        out_cb[e] = ed / csz;
        return;
    }

    // ---- fuse part ----
    __shared__ float Qs[32][65];
    __shared__ int kidx[64];
    const int n0  = blockIdx.x * 64;
    const int b   = n0 >> 10;
    const int hw0 = n0 & 1023;
    float* ob = outq + (size_t)b * (D_DIM * HW) + hw0;

    if (tid < 64) kidx[tid] = idx[n0 + tid];

    for (int d0 = 0; d0 < D_DIM; d0 += 32) {
        __syncthreads();   // protects Qs reuse (and kidx on first iter)
        #pragma unroll
        for (int h = 0; h < 2; ++h) {
            int s  = tid + 256 * h;
            int n  = s >> 3;
            int dq = s & 7;
            int k  = kidx[n];
            float4 q = *(const float4*)&cb[(size_t)k * D_DIM + d0 + dq * 4];
            Qs[dq * 4 + 0][n] = q.x;
            Qs[dq * 4 + 1][n] = q.y;
            Qs[dq * 4 + 2][n] = q.z;
            Qs[dq * 4 + 3][n] = q.w;
        }
        __syncthreads();
        #pragma unroll
        for (int j = 0; j < 8; ++j) {
            int v = tid + 256 * j;
            int d = v >> 6;
            int n = v & 63;
            ob[(size_t)(d0 + d) * HW + n] = Qs[d][n];
        }
    }
}

// ============================================================
extern "C" void kernel_launch(void* const* d_in, const int* in_sizes, int n_in,
                              void* d_out, int out_size, void* d_ws, size_t ws_size,
                              hipStream_t stream) {
    const float* z       = (const float*)d_in[0];
    const float* cb      = (const float*)d_in[1];
    const float* ema_cs  = (const float*)d_in[2];
    const float* ema_dw  = (const float*)d_in[3];
    float* out = (float*)d_out;

    char* ws = (char*)d_ws;
    float* ws_counts = (float*)(ws + WS_COUNTS);
    float* ws_cbnorm = (float*)(ws + WS_CBNORM);
    int*   ws_offs   = (int*)(ws + WS_OFFS);
    int*   ws_cursor = (int*)(ws + WS_CURSOR);
    int*   ws_idx    = (int*)(ws + WS_IDX);
    int*   ws_sorted = (int*)(ws + WS_SORTED);
    ushort* ws_cbhi  = (ushort*)(ws + WS_CBHI);
    ushort* ws_cblo  = (ushort*)(ws + WS_CBLO);
    u64*   ws_part   = (u64*)(ws + WS_PART);
    int*   ws_hist   = (int*)(ws + WS_HIST);
    float* ws_zpart  = (float*)(ws + WS_ZPART);
    float* ws_bpart  = (float*)(ws + WS_BPART);
    int*   ws_done   = (int*)(ws + WS_DONE);
    float* ws_ntot   = (float*)(ws + WS_NTOT);
    int*   ws_scode  = (int*)(ws + WS_SCODE);

    // zhi/zlo scratch lives in the OUT_Q region (exactly 32 MB)
    ushort* zhi = (ushort*)out;
    ushort* zlo = zhi + 8388608;

    prep_ztrans<<<768, 256, 0, stream>>>(z, cb, zhi, zlo, ws_cbhi, ws_cblo,
                                         ws_cbnorm, ws_zpart, ws_done);
    argmin_gemm<<<512, 512, 0, stream>>>(ws_cbhi, ws_cblo, zhi, zlo, ws_cbnorm, ws_part);
    combine2<<<128, 256, 0, stream>>>(ws_part, ws_idx, ema_cs, ws_zpart, ws_bpart,
                                      ws_hist, ws_done, ws_counts,
                                      out + OUT_NCS, out + OUT_PERP, out + OUT_LOSS,
                                      ws_ntot, ws_offs, ws_cursor);
    scatter_kernel<<<N_POS / 256, 256, 0, stream>>>(ws_idx, ws_cursor, ws_sorted,
                                                    ws_scode, out + OUT_EDW);
    dw_chunk_kernel<<<N_POS / DW_CHUNK, 256, 0, stream>>>(zhi, zlo, ws_sorted, ws_scode,
                                                          ws_offs, ws_counts, out + OUT_EDW);
    tail_fused<<<1536, 256, 0, stream>>>(cb, ws_idx, out + OUT_Q, ema_dw,
                                         out + OUT_NCS, ws_ntot,
                                         out + OUT_EDW, out + OUT_CB);
}